// Round 1
// baseline (133.564 us; speedup 1.0000x reference)
//
#include <hip/hip_runtime.h>
#include <hip/hip_bf16.h>

#define NRED 7

__device__ __forceinline__ float waveReduce(float v) {
#pragma unroll
    for (int o = 32; o > 0; o >>= 1) v += __shfl_down(v, o, 64);
    return v;
}

// Accumulator slots:
// 0: sum(-score[li])        (loss_match numerator)
// 1: count(match != -1)     (label_valid)
// 2: sum(success & label_valid)
// 3: count(indices != -1)   (pred_valid)
// 4: sum(success & pred_valid)
// 5: sum(d*d) over all 3 comps
// 6: sum over pred_valid of (d2/c + 0.12*log(c))
__global__ void setloss_partial(const float* __restrict__ scores,
                                const float* __restrict__ cov,
                                const float* __restrict__ pos,
                                const float* __restrict__ pose,
                                const int* __restrict__ indices,
                                const int* __restrict__ match,
                                float* __restrict__ part,
                                int N, int grid) {
    float acc[NRED];
#pragma unroll
    for (int k = 0; k < NRED; ++k) acc[k] = 0.0f;

    const int stride = gridDim.x * blockDim.x;
    for (int r = blockIdx.x * blockDim.x + threadIdx.x; r < N; r += stride) {
        const unsigned ur = (unsigned)r;
        const unsigned b  = ur / 31u;          // group index
        const unsigned i  = ur - b * 31u;      // row within group (0..30)

        const int mt = match[r];
        const int li = (mt < 0) ? 31 : mt;     // dustbin column m=31
        // scores[(b*(n+1) + i) * (m+1) + li], n+1 = m+1 = 32
        const float sc = scores[(size_t)(((b << 5) + i) << 5) + (unsigned)li];
        acc[0] -= sc;

        const int oi = indices[r];
        const float succ = (oi == mt) ? 1.0f : 0.0f;
        const bool lv = (mt != -1);
        const bool pv = (oi != -1);
        acc[1] += lv ? 1.0f : 0.0f;
        acc[2] += lv ? succ : 0.0f;
        acc[3] += pv ? 1.0f : 0.0f;
        acc[4] += pv ? succ : 0.0f;

        const float px = pos[3 * (size_t)r + 0];
        const float py = pos[3 * (size_t)r + 1];
        const float pz = pos[3 * (size_t)r + 2];
        const float qx = pose[7 * (size_t)r + 0];
        const float qy = pose[7 * (size_t)r + 1];
        const float qz = pose[7 * (size_t)r + 2];
        const float dx = px - qx, dy = py - qy, dz = pz - qz;
        const float d2 = dx * dx + dy * dy + dz * dz;
        acc[5] += d2;

        const float c = cov[r];
        if (pv) acc[6] += d2 / c + 0.12f * logf(c);
    }

    __shared__ float sdata[NRED][4];
    const int lane = threadIdx.x & 63;
    const int wave = threadIdx.x >> 6;
#pragma unroll
    for (int k = 0; k < NRED; ++k) {
        float v = waveReduce(acc[k]);
        if (lane == 0) sdata[k][wave] = v;
    }
    __syncthreads();
    if (threadIdx.x == 0) {
#pragma unroll
        for (int k = 0; k < NRED; ++k) {
            float v = sdata[k][0] + sdata[k][1] + sdata[k][2] + sdata[k][3];
            part[(size_t)k * grid + blockIdx.x] = v;   // SoA partials
        }
    }
}

__global__ void setloss_final(const float* __restrict__ part, int grid,
                              float* __restrict__ out, int N) {
    float acc[NRED];
#pragma unroll
    for (int k = 0; k < NRED; ++k) acc[k] = 0.0f;
    for (int t = threadIdx.x; t < grid; t += blockDim.x) {
#pragma unroll
        for (int k = 0; k < NRED; ++k) acc[k] += part[(size_t)k * grid + t];
    }
    __shared__ float sdata[NRED][4];
    const int lane = threadIdx.x & 63;
    const int wave = threadIdx.x >> 6;
#pragma unroll
    for (int k = 0; k < NRED; ++k) {
        float v = waveReduce(acc[k]);
        if (lane == 0) sdata[k][wave] = v;
    }
    __syncthreads();
    if (threadIdx.x == 0) {
        float s[NRED];
#pragma unroll
        for (int k = 0; k < NRED; ++k)
            s[k] = sdata[k][0] + sdata[k][1] + sdata[k][2] + sdata[k][3];

        const float fN = (float)N;
        const float loss_match = s[0] / fN;
        const float loss_pos   = s[5] / fN;            // mean(d*d)*3 == sum/ (3N) * 3
        const float cnt_label  = s[1];
        const float cnt_pred   = s[3];
        const float recall     = (cnt_label > 0.0f) ? s[2] / cnt_label : 1.0f;
        const float precision  = (cnt_pred  > 0.0f) ? s[4] / cnt_pred  : 1.0f;
        const float loss_cov   = (cnt_pred  > 0.0f) ? s[6] / cnt_pred  : 5.0f;
        const float total = 1.0f * loss_match + 1.0f * loss_pos + 0.1f * loss_cov;

        out[0] = total;
        out[1] = loss_match;
        out[2] = loss_pos;
        out[3] = 0.0f;        // loss_rot
        out[4] = loss_cov;
        out[5] = precision;
        out[6] = recall;
    }
}

extern "C" void kernel_launch(void* const* d_in, const int* in_sizes, int n_in,
                              void* d_out, int out_size, void* d_ws, size_t ws_size,
                              hipStream_t stream) {
    const float* scores  = (const float*)d_in[0];
    const float* cov     = (const float*)d_in[1];
    const float* pos     = (const float*)d_in[2];
    const float* pose    = (const float*)d_in[3];
    const int*   indices = (const int*)d_in[4];
    const int*   match   = (const int*)d_in[5];
    float* out = (float*)d_out;

    const int N = in_sizes[5];   // match is [N,1]

    int grid = 2048;
    const size_t need = (size_t)NRED * (size_t)grid * sizeof(float);
    if (ws_size < need) grid = (int)(ws_size / ((size_t)NRED * sizeof(float)));
    if (grid < 1) grid = 1;

    float* part = (float*)d_ws;

    setloss_partial<<<grid, 256, 0, stream>>>(scores, cov, pos, pose, indices,
                                              match, part, N, grid);
    setloss_final<<<1, 256, 0, stream>>>(part, grid, out, N);
}